// Round 22
// baseline (233.597 us; speedup 1.0000x reference)
//
#include <hip/hip_runtime.h>
#include <hip/hip_bf16.h>

#define TPB  256
#define WPB  4              // 4 waves/block; NBLK=512 -> 2 blocks/CU co-resident
#define NBLK 512
#define PROW 136            // panel row stride in shorts (272B = odd*16B)
#define PSZ  (128 * PROW)   // shorts per panel

typedef short    short8 __attribute__((ext_vector_type(8)));
typedef float    f32x4  __attribute__((ext_vector_type(4)));
typedef unsigned uint4v __attribute__((ext_vector_type(4)));

#define SBAR() __builtin_amdgcn_sched_barrier(0)

// No local arrays anywhere; named-member structs by value only.
struct Frag     { short8 k0, k1, k2, k3; };
struct FragPair { Frag t, p; };
struct Acc8     { f32x4 n0, n1, n2, n3, n4, n5, n6, n7; };
struct Acc8x3   { Acc8 a, b, c; };
struct F2       { float a, b; };

__device__ __forceinline__ f32x4 sp4(float v) { f32x4 r = {v, v, v, v}; return r; }

__device__ __forceinline__ float fast_tanh(float z) {
    float e = __expf(2.0f * z);
    return 1.0f - 2.0f * __builtin_amdgcn_rcpf(e + 1.0f);
}
__device__ __forceinline__ f32x4 tanh4(f32x4 z) {
    f32x4 r;
    r[0] = fast_tanh(z[0]); r[1] = fast_tanh(z[1]);
    r[2] = fast_tanh(z[2]); r[3] = fast_tanh(z[3]);
    return r;
}

__device__ __forceinline__ unsigned short bf16_bits(float v) {
    __hip_bfloat16 b = __float2bfloat16(v);
    unsigned short s; __builtin_memcpy(&s, &b, 2);
    return s;
}
__device__ __forceinline__ unsigned pack_bf2(float lo, float hi) {
    return (unsigned)bf16_bits(lo) | ((unsigned)bf16_bits(hi) << 16);
}
__device__ __forceinline__ short8 packB(f32x4 lo, f32x4 hi) {
    uint4v u;
    u[0] = pack_bf2(lo[0], lo[1]);
    u[1] = pack_bf2(lo[2], lo[3]);
    u[2] = pack_bf2(hi[0], hi[1]);
    u[3] = pack_bf2(hi[2], hi[3]);
    return __builtin_bit_cast(short8, u);
}
__device__ __forceinline__ float bfc(short s) {
    return __builtin_bit_cast(float, ((unsigned)(unsigned short)s) << 16);
}
__device__ __forceinline__ f32x4 unplo(short8 v) {
    f32x4 r; r[0] = bfc(v[0]); r[1] = bfc(v[1]); r[2] = bfc(v[2]); r[3] = bfc(v[3]); return r;
}
__device__ __forceinline__ f32x4 unphi(short8 v) {
    f32x4 r; r[0] = bfc(v[4]); r[1] = bfc(v[5]); r[2] = bfc(v[6]); r[3] = bfc(v[7]); return r;
}

__device__ __forceinline__ Acc8 acc_zero() {
    Acc8 A;
    A.n0 = sp4(0.f); A.n1 = sp4(0.f); A.n2 = sp4(0.f); A.n3 = sp4(0.f);
    A.n4 = sp4(0.f); A.n5 = sp4(0.f); A.n6 = sp4(0.f); A.n7 = sp4(0.f);
    return A;
}
__device__ __forceinline__ Acc8 acc_bias(const float* bp, int fb) {
    Acc8 A;
    A.n0 = *(const f32x4*)(bp + 0 * 16 + fb);
    A.n1 = *(const f32x4*)(bp + 1 * 16 + fb);
    A.n2 = *(const f32x4*)(bp + 2 * 16 + fb);
    A.n3 = *(const f32x4*)(bp + 3 * 16 + fb);
    A.n4 = *(const f32x4*)(bp + 4 * 16 + fb);
    A.n5 = *(const f32x4*)(bp + 5 * 16 + fb);
    A.n6 = *(const f32x4*)(bp + 6 * 16 + fb);
    A.n7 = *(const f32x4*)(bp + 7 * 16 + fb);
    return A;
}

// Triple GEMM sharing one A-panel pass: 32 A-frag reads feed 96 MFMAs.
// acc(96) + B(48) keeps TOTAL unified allocation (~230) under the 256 needed
// for 2 waves/SIMD HW co-residency (gemm6's ~440 total can never co-schedule:
// R20/R21 nulls). R19's spill came from the wpe(2,2)->128 arch target, not
// from this structure.
__device__ __forceinline__ Acc8x3 gemm3_frag(const unsigned short* __restrict__ pnl,
                                             int c, int g,
                                             Frag B0, Frag B1, Frag B2,
                                             Acc8 A0, Acc8 A1, Acc8 A2) {
#define ROW3(NT, N, KK, V0, V1, V2) { \
    const short8 af = *reinterpret_cast<const short8*>( \
        pnl + ((NT) * 16 + c) * PROW + (KK) * 32 + g * 8); \
    A0.N = __builtin_amdgcn_mfma_f32_16x16x32_bf16(af, V0, A0.N, 0, 0, 0); \
    A1.N = __builtin_amdgcn_mfma_f32_16x16x32_bf16(af, V1, A1.N, 0, 0, 0); \
    A2.N = __builtin_amdgcn_mfma_f32_16x16x32_bf16(af, V2, A2.N, 0, 0, 0); }
#define KS3(KK, V0, V1, V2) \
    ROW3(0, n0, KK, V0, V1, V2) ROW3(1, n1, KK, V0, V1, V2) \
    ROW3(2, n2, KK, V0, V1, V2) ROW3(3, n3, KK, V0, V1, V2) \
    ROW3(4, n4, KK, V0, V1, V2) ROW3(5, n5, KK, V0, V1, V2) \
    ROW3(6, n6, KK, V0, V1, V2) ROW3(7, n7, KK, V0, V1, V2) SBAR();
    KS3(0, B0.k0, B1.k0, B2.k0)
    KS3(1, B0.k1, B1.k1, B2.k1)
    KS3(2, B0.k2, B1.k2, B2.k2)
    KS3(3, B0.k3, B1.k3, B2.k3)
#undef KS3
#undef ROW3
    Acc8x3 R; R.a = A0; R.b = A1; R.c = A2; return R;
}

__device__ __forceinline__ float red16(float v) {
    v += __shfl_xor(v, 16, 64);
    v += __shfl_xor(v, 32, 64);
    return v;
}

// ---- layer-1: tanh ONCE per tile; seeds derive from register-resident h1 ----
__device__ __forceinline__ f32x4 h1q(const float* sP, int f0,
                                     float xt, float xx, float xy) {
    f32x4 wt = *(const f32x4*)(sP + f0);
    f32x4 wx = *(const f32x4*)(sP + 128 + f0);
    f32x4 wy = *(const f32x4*)(sP + 256 + f0);
    f32x4 bb = *(const f32x4*)(sP + 384 + f0);
    return tanh4(sp4(xt) * wt + sp4(xx) * wx + sp4(xy) * wy + bb);
}
__device__ __forceinline__ Frag make_h(const float* sP, int fb,
                                       float xt, float xx, float xy) {
    Frag F;
    F.k0 = packB(h1q(sP, 0  + fb, xt, xx, xy), h1q(sP, 64  + fb, xt, xx, xy)); SBAR();
    F.k1 = packB(h1q(sP, 16 + fb, xt, xx, xy), h1q(sP, 80  + fb, xt, xx, xy)); SBAR();
    F.k2 = packB(h1q(sP, 32 + fb, xt, xx, xy), h1q(sP, 96  + fb, xt, xx, xy)); SBAR();
    F.k3 = packB(h1q(sP, 48 + fb, xt, xx, xy), h1q(sP, 112 + fb, xt, xx, xy)); SBAR();
    return F;
}
// t1 = (1-h1^2)*wd   from cached h1
__device__ __forceinline__ Frag t_from(Frag h1, const float* wd, int fb) {
    Frag F;
#define TF(K, IL, IH) { \
    f32x4 hl = unplo(h1.K), hh = unphi(h1.K); \
    f32x4 wl = *(const f32x4*)(wd + (IL) * 16 + fb); \
    f32x4 wh = *(const f32x4*)(wd + (IH) * 16 + fb); \
    F.K = packB((sp4(1.f) - hl * hl) * wl, (sp4(1.f) - hh * hh) * wh); }
    TF(k0, 0, 4) TF(k1, 1, 5) TF(k2, 2, 6) TF(k3, 3, 7)
#undef TF
    return F;
}
// s1 = -h1*(1-h1^2)*wd^2   from cached h1
__device__ __forceinline__ Frag s_from(Frag h1, const float* wd, int fb) {
    Frag F;
#define SF(K, IL, IH) { \
    f32x4 hl = unplo(h1.K), hh = unphi(h1.K); \
    f32x4 wl = *(const f32x4*)(wd + (IL) * 16 + fb); \
    f32x4 wh = *(const f32x4*)(wd + (IH) * 16 + fb); \
    F.K = packB((sp4(0.f) - hl) * (sp4(1.f) - hl * hl) * wl * wl, \
                (sp4(0.f) - hh) * (sp4(1.f) - hh * hh) * wh * wh); }
    SF(k0, 0, 4) SF(k1, 1, 5) SF(k2, 2, 6) SF(k3, 3, 7)
#undef SF
    return F;
}

__device__ __forceinline__ Frag tanh_frag(Acc8 A) {
    Frag F;
    F.k0 = packB(tanh4(A.n0), tanh4(A.n4));
    F.k1 = packB(tanh4(A.n1), tanh4(A.n5));
    F.k2 = packB(tanh4(A.n2), tanh4(A.n6));
    F.k3 = packB(tanh4(A.n3), tanh4(A.n7));
    return F;
}

// t2 = a2*tz2 (no p-term)
__device__ __forceinline__ Frag t2only(Frag h, Acc8 T) {
    Frag R;
#define TO(K, NL, NH) { \
    f32x4 hl = unplo(h.K), hh = unphi(h.K); \
    R.K = packB((sp4(1.f) - hl * hl) * T.NL, (sp4(1.f) - hh * hh) * T.NH); }
    TO(k0, n0, n4) TO(k1, n1, n5) TO(k2, n2, n6) TO(k3, n3, n7)
#undef TO
    return R;
}

// t = a*tz ; p = -h*a*tz^2  (verified round 7)
__device__ __forceinline__ FragPair tjet(Frag h, Acc8 T) {
    FragPair R;
#define TP(K, NL, NH) { \
    f32x4 hl = unplo(h.K), hh = unphi(h.K); \
    f32x4 tl = (sp4(1.f) - hl * hl) * T.NL, th = (sp4(1.f) - hh * hh) * T.NH; \
    R.t.K = packB(tl, th); \
    R.p.K = packB((sp4(0.f) - hl) * tl * T.NL, (sp4(0.f) - hh) * th * T.NH); }
    TP(k0, n0, n4) TP(k1, n1, n5) TP(k2, n2, n6) TP(k3, n3, n7)
#undef TP
    return R;
}

// s = a*sz + p  (verified round 7)
__device__ __forceinline__ Frag sjet(Frag h, Acc8 S, Frag p) {
    Frag R;
#define SJ(K, NL, NH) { \
    f32x4 hl = unplo(h.K), hh = unphi(h.K); \
    R.K = packB((sp4(1.f) - hl * hl) * S.NL + unplo(p.K), \
                (sp4(1.f) - hh * hh) * S.NH + unphi(p.K)); }
    SJ(k0, n0, n4) SJ(k1, n1, n5) SJ(k2, n2, n6) SJ(k3, n3, n7)
#undef SJ
    return R;
}

// h3 = tanh(acc), cp = sum w4*h3
__device__ __forceinline__ Frag tanh_dotw4(const float* w4p, int fb, Acc8 A, float& cp) {
    Frag F; f32x4 s = sp4(0.f);
#define TD(K, NL, NH, IL, IH) { \
    f32x4 hl = tanh4(A.NL), hh = tanh4(A.NH); \
    f32x4 wl = *(const f32x4*)(w4p + (IL) * 16 + fb); \
    f32x4 wh = *(const f32x4*)(w4p + (IH) * 16 + fb); \
    s += wl * hl + wh * hh; \
    F.K = packB(hl, hh); }
    TD(k0, n0, n4, 0, 4) TD(k1, n1, n5, 1, 5) TD(k2, n2, n6, 2, 6) TD(k3, n3, n7, 3, 7)
#undef TD
    cp = s[0] + s[1] + s[2] + s[3];
    return F;
}

// a = sum w4*a3*T ; b = -sum w4*a3*h3*T^2
__device__ __forceinline__ F2 dot_tz(const float* w4p, int fb, Frag h, Acc8 T) {
    f32x4 s1 = sp4(0.f), s2 = sp4(0.f);
#define DT(K, NL, NH, IL, IH) { \
    f32x4 wl = *(const f32x4*)(w4p + (IL) * 16 + fb); \
    f32x4 wh = *(const f32x4*)(w4p + (IH) * 16 + fb); \
    f32x4 hl = unplo(h.K), hh = unphi(h.K); \
    f32x4 wal = wl * (sp4(1.f) - hl * hl), wah = wh * (sp4(1.f) - hh * hh); \
    s1 += wal * T.NL + wah * T.NH; \
    s2 -= wal * hl * T.NL * T.NL + wah * hh * T.NH * T.NH; }
    DT(k0, n0, n4, 0, 4) DT(k1, n1, n5, 1, 5) DT(k2, n2, n6, 2, 6) DT(k3, n3, n7, 3, 7)
#undef DT
    F2 r; r.a = s1[0] + s1[1] + s1[2] + s1[3]; r.b = s2[0] + s2[1] + s2[2] + s2[3];
    return r;
}

// sum w4*a3*S
__device__ __forceinline__ float dot_wa(const float* w4p, int fb, Frag h, Acc8 S) {
    f32x4 s = sp4(0.f);
#define DA(K, NL, NH, IL, IH) { \
    f32x4 wl = *(const f32x4*)(w4p + (IL) * 16 + fb); \
    f32x4 wh = *(const f32x4*)(w4p + (IH) * 16 + fb); \
    f32x4 hl = unplo(h.K), hh = unphi(h.K); \
    s += wl * (sp4(1.f) - hl * hl) * S.NL + wh * (sp4(1.f) - hh * hh) * S.NH; }
    DA(k0, n0, n4, 0, 4) DA(k1, n1, n5, 1, 5) DA(k2, n2, n6, 2, 6) DA(k3, n3, n7, 3, 7)
#undef DA
    return s[0] + s[1] + s[2] + s[3];
}

// wpe(1,2): min=1 -> 256-reg compile target (no spill for ~230 peak); max=2
// permits 2 waves/SIMD. gemm3 keeps TOTAL unified allocation ~230 <= 256 so
// the HW can actually co-schedule two waves (gemm6's ~440 total could not).
__global__ __launch_bounds__(TPB, 1) __attribute__((amdgpu_waves_per_eu(1, 2)))
void mlp_jet_kernel(
    const float* __restrict__ X,
    const float* __restrict__ gW1, const float* __restrict__ gB1,
    const float* __restrict__ gW2, const float* __restrict__ gB2,
    const float* __restrict__ gW3, const float* __restrict__ gB3,
    const float* __restrict__ gW4, const float* __restrict__ gB4,
    float* __restrict__ out, int N)
{
    __shared__ alignas(16) unsigned short sPanel[2 * PSZ];           // 69632 B
    __shared__ alignas(16) float sParam[7 * 128];                    // 3584 B -> 73216 total

    const int tid = threadIdx.x;
    for (int idx = tid; idx < 2 * 128 * 128; idx += TPB) {
        int p = idx >> 14, e = idx & 16383, n = e >> 7, pp = e & 127;
        int kk = pp >> 5, gg = (pp >> 3) & 3, jj = pp & 7;
        int f = ((((jj >> 2) << 2) | kk) << 4) | (gg << 2) | (jj & 3);  // invsigma
        const float* Wsrc = p ? gW3 : gW2;
        sPanel[p * PSZ + n * PROW + pp] = bf16_bits(Wsrc[f * 128 + n]);
    }
    if (tid < 128) {
        sParam[0 * 128 + tid] = gW1[tid];
        sParam[1 * 128 + tid] = gW1[128 + tid];
        sParam[2 * 128 + tid] = gW1[256 + tid];
        sParam[3 * 128 + tid] = gB1[tid];
        sParam[4 * 128 + tid] = gB2[tid];
        sParam[5 * 128 + tid] = gB3[tid];
        sParam[6 * 128 + tid] = gW4[tid];
    }
    __syncthreads();

    const int lane = tid & 63;
    const int wave = tid >> 6;
    const int c = lane & 15, g = lane >> 4;
    const int fb = g << 2;
    const unsigned short* const pW2f = sPanel;
    const unsigned short* const pW3f = sPanel + PSZ;
    const float b4 = gB4[0];
    const float* const w4p = sParam + 6 * 128;

    const int tiles = N >> 4;
    for (int t = blockIdx.x * WPB + wave; t < tiles; t += NBLK * WPB) {
        const int sbase = t << 4;
        const float* xp = X + (long)(sbase + c) * 3;
        const float xt = xp[0], xx = xp[1], xy = xp[2];

        // ---- layer 1: h1 (register-resident) + x/y first-order seeds ----
        Frag h1F = make_h(sParam, fb, xt, xx, xy);
        Frag t1x = t_from(h1F, sParam + 128, fb);
        Frag t1y = t_from(h1F, sParam + 256, fb);

        // ---- P1: z2 | tz2x | tz2y ----
        Acc8x3 R = gemm3_frag(pW2f, c, g, h1F, t1x, t1y,
                              acc_bias(sParam + 4 * 128, fb), acc_zero(), acc_zero());
        Frag h2F = tanh_frag(R.a);
        FragPair TPx = tjet(h2F, R.b);
        FragPair TPy = tjet(h2F, R.c);

        // ---- P2: z3 | tz3x | tz3y (consume t-frags immediately) ----
        R = gemm3_frag(pW3f, c, g, h2F, TPx.t, TPy.t,
                       acc_bias(sParam + 5 * 128, fb), acc_zero(), acc_zero());
        float cp;
        Frag h3F = tanh_dotw4(w4p, fb, R.a, cp);
        cp = red16(cp);
        if (lane < 16) out[sbase + lane] = cp + b4;
        F2 rx = dot_tz(w4p, fb, h3F, R.b);
        float c1x = red16(rx.a);
        if (lane < 16) out[2L * N + sbase + lane] = c1x;
        F2 ry = dot_tz(w4p, fb, h3F, R.c);
        float c1y = red16(ry.a);
        if (lane < 16) out[3L * N + sbase + lane] = c1y;

        // ---- P3: tz2t | sz2x | sz2y (seeds re-derived; h1 dies here) ----
        Frag t1t = t_from(h1F, sParam, fb);
        Frag s1x = s_from(h1F, sParam + 128, fb);
        Frag s1y = s_from(h1F, sParam + 256, fb);
        R = gemm3_frag(pW2f, c, g, t1t, s1x, s1y,
                       acc_zero(), acc_zero(), acc_zero());
        Frag t2t = t2only(h2F, R.a);
        Frag s2x = sjet(h2F, R.b, TPx.p);
        Frag s2y = sjet(h2F, R.c, TPy.p);

        // ---- P4: tz3t | sz3x | sz3y ----
        R = gemm3_frag(pW3f, c, g, t2t, s2x, s2y,
                       acc_zero(), acc_zero(), acc_zero());
        float c1t = red16(dot_wa(w4p, fb, h3F, R.a));
        if (lane < 16) out[(long)N + sbase + lane] = c1t;
        float c2x = rx.b + dot_wa(w4p, fb, h3F, R.b);
        float c2y = ry.b + dot_wa(w4p, fb, h3F, R.c);
        c2x = red16(c2x);
        c2y = red16(c2y);
        if (lane < 16) {
            out[4L * N + sbase + lane] = 2.f * c2x;
            out[5L * N + sbase + lane] = 2.f * c2y;
        }
    }
}

extern "C" void kernel_launch(void* const* d_in, const int* in_sizes, int n_in,
                              void* d_out, int out_size, void* d_ws, size_t ws_size,
                              hipStream_t stream) {
    const float* X  = (const float*)d_in[0];
    const float* W1 = (const float*)d_in[1];
    const float* B1 = (const float*)d_in[2];
    const float* W2 = (const float*)d_in[3];
    const float* B2 = (const float*)d_in[4];
    const float* W3 = (const float*)d_in[5];
    const float* B3 = (const float*)d_in[6];
    const float* W4 = (const float*)d_in[7];
    const float* B4 = (const float*)d_in[8];
    float* out = (float*)d_out;
    const int N = in_sizes[0] / 3;

    mlp_jet_kernel<<<NBLK, TPB, 0, stream>>>(X, W1, B1, W2, B2, W3, B3, W4, B4, out, N);
}

// Round 23
// 154.242 us; speedup vs baseline: 1.5145x; 1.5145x over previous
//
#include <hip/hip_runtime.h>
#include <hip/hip_bf16.h>

#define TPB  256
#define WPB  4              // waves per block; 1 block/CU (serial regime, R18)
#define NBLK 256
#define PROW 136            // panel row stride in shorts (272B = odd*16B)
#define PSZ  (128 * PROW)   // shorts per panel

typedef short    short8 __attribute__((ext_vector_type(8)));
typedef float    f32x4  __attribute__((ext_vector_type(4)));
typedef unsigned uint4v __attribute__((ext_vector_type(4)));

#define SBAR() __builtin_amdgcn_sched_barrier(0)

// No local arrays anywhere; named-member structs by value only.
struct Frag   { short8 k0, k1, k2, k3; };
struct Acc8   { f32x4 n0, n1, n2, n3, n4, n5, n6, n7; };
struct Acc8x6 { Acc8 a, b, c, d, e, f; };

__device__ __forceinline__ f32x4 sp4(float v) { f32x4 r = {v, v, v, v}; return r; }

__device__ __forceinline__ float fast_tanh(float z) {
    float e = __expf(2.0f * z);
    return 1.0f - 2.0f * __builtin_amdgcn_rcpf(e + 1.0f);
}
__device__ __forceinline__ f32x4 tanh4(f32x4 z) {
    f32x4 r;
    r[0] = fast_tanh(z[0]); r[1] = fast_tanh(z[1]);
    r[2] = fast_tanh(z[2]); r[3] = fast_tanh(z[3]);
    return r;
}

__device__ __forceinline__ unsigned short bf16_bits(float v) {
    __hip_bfloat16 b = __float2bfloat16(v);
    unsigned short s; __builtin_memcpy(&s, &b, 2);
    return s;
}
__device__ __forceinline__ unsigned pack_bf2(float lo, float hi) {
    return (unsigned)bf16_bits(lo) | ((unsigned)bf16_bits(hi) << 16);
}
__device__ __forceinline__ short8 packB(f32x4 lo, f32x4 hi) {
    uint4v u;
    u[0] = pack_bf2(lo[0], lo[1]);
    u[1] = pack_bf2(lo[2], lo[3]);
    u[2] = pack_bf2(hi[0], hi[1]);
    u[3] = pack_bf2(hi[2], hi[3]);
    return __builtin_bit_cast(short8, u);
}

__device__ __forceinline__ Acc8 acc_zero() {
    Acc8 A;
    A.n0 = sp4(0.f); A.n1 = sp4(0.f); A.n2 = sp4(0.f); A.n3 = sp4(0.f);
    A.n4 = sp4(0.f); A.n5 = sp4(0.f); A.n6 = sp4(0.f); A.n7 = sp4(0.f);
    return A;
}
__device__ __forceinline__ Acc8 acc_bias(const float* bp, int fb) {
    Acc8 A;
    A.n0 = *(const f32x4*)(bp + 0 * 16 + fb);
    A.n1 = *(const f32x4*)(bp + 1 * 16 + fb);
    A.n2 = *(const f32x4*)(bp + 2 * 16 + fb);
    A.n3 = *(const f32x4*)(bp + 3 * 16 + fb);
    A.n4 = *(const f32x4*)(bp + 4 * 16 + fb);
    A.n5 = *(const f32x4*)(bp + 5 * 16 + fb);
    A.n6 = *(const f32x4*)(bp + 6 * 16 + fb);
    A.n7 = *(const f32x4*)(bp + 7 * 16 + fb);
    return A;
}

// Hex GEMM sharing one A-panel pass: 32 A-frag reads feed 192 MFMAs (six
// B-streams). One pass per layer -> 64 panel reads/tile, zero jet-LDS traffic.
__device__ __forceinline__ Acc8x6 gemm6_frag(const unsigned short* __restrict__ pnl,
                                             int c, int g,
                                             Frag B0, Frag B1, Frag B2,
                                             Frag B3, Frag B4, Frag B5,
                                             Acc8 A0, Acc8 A1, Acc8 A2,
                                             Acc8 A3, Acc8 A4, Acc8 A5) {
#define ROW6(NT, N, KK, V0, V1, V2, V3, V4, V5) { \
    const short8 af = *reinterpret_cast<const short8*>( \
        pnl + ((NT) * 16 + c) * PROW + (KK) * 32 + g * 8); \
    A0.N = __builtin_amdgcn_mfma_f32_16x16x32_bf16(af, V0, A0.N, 0, 0, 0); \
    A1.N = __builtin_amdgcn_mfma_f32_16x16x32_bf16(af, V1, A1.N, 0, 0, 0); \
    A2.N = __builtin_amdgcn_mfma_f32_16x16x32_bf16(af, V2, A2.N, 0, 0, 0); \
    A3.N = __builtin_amdgcn_mfma_f32_16x16x32_bf16(af, V3, A3.N, 0, 0, 0); \
    A4.N = __builtin_amdgcn_mfma_f32_16x16x32_bf16(af, V4, A4.N, 0, 0, 0); \
    A5.N = __builtin_amdgcn_mfma_f32_16x16x32_bf16(af, V5, A5.N, 0, 0, 0); }
#define KS6(KK, V0, V1, V2, V3, V4, V5) \
    ROW6(0, n0, KK, V0, V1, V2, V3, V4, V5) ROW6(1, n1, KK, V0, V1, V2, V3, V4, V5) \
    ROW6(2, n2, KK, V0, V1, V2, V3, V4, V5) ROW6(3, n3, KK, V0, V1, V2, V3, V4, V5) \
    ROW6(4, n4, KK, V0, V1, V2, V3, V4, V5) ROW6(5, n5, KK, V0, V1, V2, V3, V4, V5) \
    ROW6(6, n6, KK, V0, V1, V2, V3, V4, V5) ROW6(7, n7, KK, V0, V1, V2, V3, V4, V5) SBAR();
    KS6(0, B0.k0, B1.k0, B2.k0, B3.k0, B4.k0, B5.k0)
    KS6(1, B0.k1, B1.k1, B2.k1, B3.k1, B4.k1, B5.k1)
    KS6(2, B0.k2, B1.k2, B2.k2, B3.k2, B4.k2, B5.k2)
    KS6(3, B0.k3, B1.k3, B2.k3, B3.k3, B4.k3, B5.k3)
#undef KS6
#undef ROW6
    Acc8x6 R; R.a = A0; R.b = A1; R.c = A2; R.d = A3; R.e = A4; R.f = A5; return R;
}

__device__ __forceinline__ float red16(float v) {
    v += __shfl_xor(v, 16, 64);
    v += __shfl_xor(v, 32, 64);
    return v;
}
__device__ __forceinline__ float hsum4(f32x4 v) {
    return (v[0] + v[1]) + (v[2] + v[3]);
}

__global__ __launch_bounds__(TPB, 1) __attribute__((amdgpu_waves_per_eu(1)))
void mlp_jet_kernel(
    const float* __restrict__ X,
    const float* __restrict__ gW1, const float* __restrict__ gB1,
    const float* __restrict__ gW2, const float* __restrict__ gB2,
    const float* __restrict__ gW3, const float* __restrict__ gB3,
    const float* __restrict__ gW4, const float* __restrict__ gB4,
    float* __restrict__ out, int N)
{
    __shared__ alignas(16) unsigned short sPanel[2 * PSZ];           // 69632 B
    __shared__ alignas(16) float sParam[7 * 128];                    // 3584 B -> 73216 total

    const int tid = threadIdx.x;
    for (int idx = tid; idx < 2 * 128 * 128; idx += TPB) {
        int p = idx >> 14, e = idx & 16383, n = e >> 7, pp = e & 127;
        int kk = pp >> 5, gg = (pp >> 3) & 3, jj = pp & 7;
        int f = ((((jj >> 2) << 2) | kk) << 4) | (gg << 2) | (jj & 3);  // invsigma
        const float* Wsrc = p ? gW3 : gW2;
        sPanel[p * PSZ + n * PROW + pp] = bf16_bits(Wsrc[f * 128 + n]);
    }
    if (tid < 128) {
        sParam[0 * 128 + tid] = gW1[tid];
        sParam[1 * 128 + tid] = gW1[128 + tid];
        sParam[2 * 128 + tid] = gW1[256 + tid];
        sParam[3 * 128 + tid] = gB1[tid];
        sParam[4 * 128 + tid] = gB2[tid];
        sParam[5 * 128 + tid] = gB3[tid];
        sParam[6 * 128 + tid] = gW4[tid];
    }
    __syncthreads();

    const int lane = tid & 63;
    const int wave = tid >> 6;
    const int c = lane & 15, g = lane >> 4;
    const int fb = g << 2;
    const unsigned short* const pW2f = sPanel;
    const unsigned short* const pW3f = sPanel + PSZ;
    const float b4 = gB4[0];
    const float* const w4p = sParam + 6 * 128;

    const int tiles = N >> 4;
    for (int t = blockIdx.x * WPB + wave; t < tiles; t += NBLK * WPB) {
        const int sbase = t << 4;
        const float* xp = X + (long)(sbase + c) * 3;
        const float xt = xp[0], xx = xp[1], xy = xp[2];

        // ---- FUSED layer-1 seeds: one pass builds all 6 operand frags.
        // h1 stays in f32 within each quad; w-vectors loaded ONCE (R18
        // reloaded wd per t_from/s_from and unpacked h1F 5x).
        Frag h1F, t1t, t1x, t1y, s1x, s1y;
#define SEED(K, IL, IH) { \
    const int fL = (IL) * 16 + fb, fH = (IH) * 16 + fb; \
    f32x4 wtL = *(const f32x4*)(sParam + fL),        wtH = *(const f32x4*)(sParam + fH); \
    f32x4 wxL = *(const f32x4*)(sParam + 128 + fL),  wxH = *(const f32x4*)(sParam + 128 + fH); \
    f32x4 wyL = *(const f32x4*)(sParam + 256 + fL),  wyH = *(const f32x4*)(sParam + 256 + fH); \
    f32x4 bbL = *(const f32x4*)(sParam + 384 + fL),  bbH = *(const f32x4*)(sParam + 384 + fH); \
    f32x4 hL = tanh4(sp4(xt) * wtL + sp4(xx) * wxL + sp4(xy) * wyL + bbL); \
    f32x4 hH = tanh4(sp4(xt) * wtH + sp4(xx) * wxH + sp4(xy) * wyH + bbH); \
    f32x4 aL = sp4(1.f) - hL * hL, aH = sp4(1.f) - hH * hH; \
    h1F.K = packB(hL, hH); \
    t1t.K = packB(aL * wtL, aH * wtH); \
    t1x.K = packB(aL * wxL, aH * wxH); \
    t1y.K = packB(aL * wyL, aH * wyH); \
    s1x.K = packB((sp4(0.f) - hL) * aL * wxL * wxL, (sp4(0.f) - hH) * aH * wxH * wxH); \
    s1y.K = packB((sp4(0.f) - hL) * aL * wyL * wyL, (sp4(0.f) - hH) * aH * wyH * wyH); \
    SBAR(); }
        SEED(k0, 0, 4) SEED(k1, 1, 5) SEED(k2, 2, 6) SEED(k3, 3, 7)
#undef SEED

        // ---- layer 2 (ONE panel pass): z2 | tz2t | tz2x | tz2y | sz2x | sz2y ----
        Acc8x6 R6 = gemm6_frag(pW2f, c, g, h1F, t1t, t1x, t1y, s1x, s1y,
                               acc_bias(sParam + 4 * 128, fb),
                               acc_zero(), acc_zero(), acc_zero(),
                               acc_zero(), acc_zero());

        // ---- FUSED layer-2 post: one pass over the 6 accs. h2 used in f32
        // directly (R18: packed then unpacked 5x); p-terms never packed.
        Frag h2F, t2t, txF, tyF, s2xF, s2yF;
#define POST2(K, NL, NH) { \
    f32x4 hL = tanh4(R6.a.NL), hH = tanh4(R6.a.NH); \
    f32x4 aL = sp4(1.f) - hL * hL, aH = sp4(1.f) - hH * hH; \
    h2F.K = packB(hL, hH); \
    t2t.K = packB(aL * R6.b.NL, aH * R6.b.NH); \
    f32x4 txL = aL * R6.c.NL, txH = aH * R6.c.NH; \
    txF.K = packB(txL, txH); \
    f32x4 pxL = (sp4(0.f) - hL) * txL * R6.c.NL, pxH = (sp4(0.f) - hH) * txH * R6.c.NH; \
    f32x4 tyL = aL * R6.d.NL, tyH = aH * R6.d.NH; \
    tyF.K = packB(tyL, tyH); \
    f32x4 pyL = (sp4(0.f) - hL) * tyL * R6.d.NL, pyH = (sp4(0.f) - hH) * tyH * R6.d.NH; \
    s2xF.K = packB(aL * R6.e.NL + pxL, aH * R6.e.NH + pxH); \
    s2yF.K = packB(aL * R6.f.NL + pyL, aH * R6.f.NH + pyH); \
    SBAR(); }
        POST2(k0, n0, n4) POST2(k1, n1, n5) POST2(k2, n2, n6) POST2(k3, n3, n7)
#undef POST2

        // ---- layer 3 (ONE panel pass): z3 | tz3t | tz3x | tz3y | sz3x | sz3y ----
        R6 = gemm6_frag(pW3f, c, g, h2F, t2t, txF, tyF, s2xF, s2yF,
                        acc_bias(sParam + 5 * 128, fb),
                        acc_zero(), acc_zero(), acc_zero(),
                        acc_zero(), acc_zero());

        // ---- FUSED layer-3 dots: one pass, w4 loaded once, h3 never packed,
        // all 9 reductions accumulated together (R18: 6 separate passes each
        // reloading w4 and unpacking h3F).
        {
            f32x4 scp = sp4(0.f), sc1t = sp4(0.f);
            f32x4 srxa = sp4(0.f), srxb = sp4(0.f);
            f32x4 srya = sp4(0.f), sryb = sp4(0.f);
            f32x4 sc2x = sp4(0.f), sc2y = sp4(0.f);
#define DOTS(NL, NH, IL, IH) { \
    f32x4 w4L = *(const f32x4*)(w4p + (IL) * 16 + fb); \
    f32x4 w4H = *(const f32x4*)(w4p + (IH) * 16 + fb); \
    f32x4 hL = tanh4(R6.a.NL), hH = tanh4(R6.a.NH); \
    f32x4 waL = w4L * (sp4(1.f) - hL * hL), waH = w4H * (sp4(1.f) - hH * hH); \
    scp  += w4L * hL + w4H * hH; \
    sc1t += waL * R6.b.NL + waH * R6.b.NH; \
    srxa += waL * R6.c.NL + waH * R6.c.NH; \
    srxb -= waL * hL * R6.c.NL * R6.c.NL + waH * hH * R6.c.NH * R6.c.NH; \
    srya += waL * R6.d.NL + waH * R6.d.NH; \
    sryb -= waL * hL * R6.d.NL * R6.d.NL + waH * hH * R6.d.NH * R6.d.NH; \
    sc2x += waL * R6.e.NL + waH * R6.e.NH; \
    sc2y += waL * R6.f.NL + waH * R6.f.NH; \
    SBAR(); }
            DOTS(n0, n4, 0, 4) DOTS(n1, n5, 1, 5) DOTS(n2, n6, 2, 6) DOTS(n3, n7, 3, 7)
#undef DOTS
            float cp  = red16(hsum4(scp));
            float c1t = red16(hsum4(sc1t));
            float c1x = red16(hsum4(srxa));
            float c1y = red16(hsum4(srya));
            float c2x = red16(hsum4(srxb) + hsum4(sc2x));
            float c2y = red16(hsum4(sryb) + hsum4(sc2y));
            if (lane < 16) {
                out[sbase + lane]           = cp + b4;
                out[(long)N + sbase + lane] = c1t;
                out[2L * N + sbase + lane]  = c1x;
                out[3L * N + sbase + lane]  = c1y;
                out[4L * N + sbase + lane]  = 2.f * c2x;
                out[5L * N + sbase + lane]  = 2.f * c2y;
            }
        }
    }
}

extern "C" void kernel_launch(void* const* d_in, const int* in_sizes, int n_in,
                              void* d_out, int out_size, void* d_ws, size_t ws_size,
                              hipStream_t stream) {
    const float* X  = (const float*)d_in[0];
    const float* W1 = (const float*)d_in[1];
    const float* B1 = (const float*)d_in[2];
    const float* W2 = (const float*)d_in[3];
    const float* B2 = (const float*)d_in[4];
    const float* W3 = (const float*)d_in[5];
    const float* B3 = (const float*)d_in[6];
    const float* W4 = (const float*)d_in[7];
    const float* B4 = (const float*)d_in[8];
    float* out = (float*)d_out;
    const int N = in_sizes[0] / 3;

    mlp_jet_kernel<<<NBLK, TPB, 0, stream>>>(X, W1, B1, W2, B2, W3, B3, W4, B4, out, N);
}